// Round 12
// baseline (307.975 us; speedup 1.0000x reference)
//
#include <hip/hip_runtime.h>
#include <math.h>

#define BB 1024
#define LL 34
#define DD 128
#define AA 4096
#define NROWS (BB * LL)        // 34816
#define RTILES (NROWS / 16)    // 2176 row tiles
#define ATILES (AA / 16)       // 256 atom tiles
#define NSPLIT 8
#define TPS (ATILES / NSPLIT)  // 32 tiles per split
#define TAU 2.5e-3f
#define SCOREBLKS ((RTILES / 16) * NSPLIT)   // 1088
#define GTABBLKS (LL * 32)                   // 1088
#define PREPEA ((RTILES + ATILES) / 4)       // 608 blocks x 4 tiles

typedef _Float16 f16;
typedef _Float16 f16x8 __attribute__((ext_vector_type(8)));
typedef float f32x4  __attribute__((ext_vector_type(4)));

// ---- ws layout (bytes), total ~24.9 MB ----
#define OFF_EMBA   0u            // RTILES*4096 (f16 emb frags, A-layout)
#define OFF_ATOMB  8912896u      // ATILES*4096 (f16 atoms_n frags)
#define OFF_WFRAG  9961472u      // 34*3*4*64*16 (f16 W frags, B-layout, N pad 48)
#define OFF_G      10379264u     // 34*4096*36*2 = 10,027,008  (G[l][a][36] f16)
#define OFF_PQ     20406272u     // NROWS*NSPLIT*16
#define OFF_INVN64 24862720u
#define OFF_INVNF  24895488u

// ---------------------------------------------------------------- k_prep
// 4 tiles per block (608 blocks) + 34 W blocks. LDS-bounced coalesced loads.
__global__ __launch_bounds__(256) void k_prep(const float* __restrict__ emb,
                                              const float* __restrict__ atoms,
                                              const float* __restrict__ W,
                                              double* __restrict__ invn64,
                                              float* __restrict__ invnF,
                                              f16x8* __restrict__ embA,
                                              f16x8* __restrict__ atomB,
                                              f16x8* __restrict__ wfrag) {
    __shared__ __align__(16) float stbuf[4608];     // 18432 B
    __shared__ double part[16][17];
    const int bid = blockIdx.x;
    const int tid = threadIdx.x;

    if (bid < PREPEA) {                             // emb/atom tiles, 4 per block
        #pragma unroll 1
        for (int tt = 0; tt < 4; tt++) {
            const int gtile = bid * 4 + tt;         // 0..2431
            const bool isAtom = (gtile >= RTILES);
            const int tile = isAtom ? gtile - RTILES : gtile;
            const float* src = (isAtom ? atoms : emb) + (size_t)tile * 2048;
            float4* st4 = (float4*)stbuf;
            for (int i = tid; i < 512; i += 256) {  // coalesced 8 KB stage
                int row = i >> 5, c4 = i & 31;
                st4[row * 33 + c4] = ((const float4*)src)[i];
            }
            __syncthreads();

            const int ks = tid >> 6, l = tid & 63;
            const int m = l & 15, koff4 = ((l >> 4) << 1) + (ks << 3);
            float4 f0 = st4[m * 33 + koff4];
            float4 f1 = st4[m * 33 + koff4 + 1];
            float xs[8] = {f0.x, f0.y, f0.z, f0.w, f1.x, f1.y, f1.z, f1.w};

            if (!isAtom) {
                f16x8 h;
                #pragma unroll
                for (int j = 0; j < 8; j++) h[j] = (f16)xs[j];
                embA[(size_t)(tile * 4 + ks) * 64 + l] = h;
            } else {
                double ssq = 0.0;
                #pragma unroll
                for (int j = 0; j < 8; j++) ssq += (double)xs[j] * xs[j];
                part[m][ks * 4 + (l >> 4)] = ssq;
                __syncthreads();
                double tot = 0.0;
                #pragma unroll
                for (int q = 0; q < 16; q++) tot += part[m][q];
                double n = sqrt(tot);
                if (n < 1e-12) n = 1e-12;
                double inv = 1.0 / n;
                float invf = (float)inv;
                f16x8 h;
                #pragma unroll
                for (int j = 0; j < 8; j++) h[j] = (f16)(xs[j] * invf);
                if (ks == 0 && (l >> 4) == 0) {
                    invn64[tile * 16 + m] = inv;
                    invnF[tile * 16 + m] = invf;
                }
                atomB[(size_t)(tile * 4 + ks) * 64 + l] = h;
            }
            __syncthreads();                        // st4/part reuse guard
        }
    } else {                                        // W fragment build, one l
        const int l = bid - PREPEA;                 // 0..33
        const float* wsrc = W + (size_t)l * 128 * LL;
        for (int i = tid; i < 128 * LL; i += 256) { // coalesced 17.4 KB stage
            int row = i / LL, j = i - row * LL;
            stbuf[row * 35 + j] = wsrc[i];
        }
        __syncthreads();
        for (int s = tid; s < 768; s += 256) {
            int lane = s & 63, ksnt = s >> 6;
            int ks = ksnt & 3, nt = ksnt >> 2;
            int j = nt * 16 + (lane & 15);
            int kb = ks * 32 + ((lane >> 4) << 3);
            f16x8 h;
            if (j < LL) {
                #pragma unroll
                for (int jj = 0; jj < 8; jj++) h[jj] = (f16)stbuf[(kb + jj) * 35 + j];
            } else {
                #pragma unroll
                for (int jj = 0; jj < 8; jj++) h[jj] = (f16)0.f;
            }
            wfrag[(size_t)((l * 3 + nt) * 4 + ks) * 64 + lane] = h;
        }
    }
}

// ---------------------------------------------------------------- k_score
// Blocks [0,1088): barrier-free f16 MFMA screen, depth-2 register prefetch
// (4 B-buffers; loads issued ~2 compute-blocks ahead of use). XCD swizzle
// bid = sp*136+rb keeps each XCD's embA slice + atomB L2-resident.
// Blocks [1088,2176): G-table build (G[l][a][36] f16, LDS-staged linear).
__global__ __launch_bounds__(256, 3) void k_score(const f16x8* __restrict__ embA,
                                                  const char* __restrict__ atomB,
                                                  const f16x8* __restrict__ wfrag,
                                                  f16* __restrict__ Gh,
                                                  float4* __restrict__ pq) {
    const int tid = threadIdx.x;
    const int w = tid >> 6, l = tid & 63;

    if (blockIdx.x >= SCOREBLKS) {
        // ---------------- gtab path: 128 atoms x one l per block
        __shared__ __align__(16) float gs[128 * 36];   // 18432 B
        const int gb = blockIdx.x - SCOREBLKS;
        const int ll = gb >> 5, ab = gb & 31;

        f16x8 bw[3][4];
        #pragma unroll
        for (int nt = 0; nt < 3; nt++)
            #pragma unroll
            for (int ks = 0; ks < 4; ks++)
                bw[nt][ks] = wfrag[(size_t)((ll * 3 + nt) * 4 + ks) * 64 + l];

        const int col = l & 15, rq = (l >> 4) * 4;
        #pragma unroll
        for (int t = 0; t < 2; t++) {
            int atile = ab * 8 + w * 2 + t;
            f16x8 ah[4];
            #pragma unroll
            for (int ks = 0; ks < 4; ks++)
                ah[ks] = *(const f16x8*)(atomB + ((size_t)(atile * 4 + ks) * 64 + l) * 16);
            f32x4 acc[3];
            #pragma unroll
            for (int nt = 0; nt < 3; nt++) acc[nt] = (f32x4){0.f, 0.f, 0.f, 0.f};
            #pragma unroll
            for (int ks = 0; ks < 4; ks++)
                #pragma unroll
                for (int nt = 0; nt < 3; nt++)
                    acc[nt] = __builtin_amdgcn_mfma_f32_16x16x32_f16(ah[ks], bw[nt][ks], acc[nt], 0, 0, 0);
            int aloc0 = (w * 2 + t) * 16 + rq;
            #pragma unroll
            for (int nt = 0; nt < 3; nt++) {
                int j = nt * 16 + col;
                if (j < LL) {
                    #pragma unroll
                    for (int r = 0; r < 4; r++)
                        gs[(aloc0 + r) * 36 + j] = acc[nt][r];
                }
            }
        }
        __syncthreads();
        f16* Gl = Gh + ((size_t)ll * 4096 + ab * 128) * 36;
        for (int i = tid; i < 128 * 36; i += 256) Gl[i] = (f16)gs[i];
        return;
    }

    // ---------------- score path (no LDS, no __syncthreads)
    const int sp = blockIdx.x / 136, rb = blockIdx.x - sp * 136;
    const int rt0 = rb * 16 + w * 4;

    f16x8 a[4][4];
    #pragma unroll
    for (int f = 0; f < 4; f++)
        #pragma unroll
        for (int ks = 0; ks < 4; ks++)
            a[f][ks] = embA[(size_t)((rt0 + f) * 4 + ks) * 64 + l];

    float v1[16], v2[16];
    #pragma unroll
    for (int s = 0; s < 16; s++) { v1[s] = -3e38f; v2[s] = -3e38f; }

    const f16x8* bbase = (const f16x8*)(atomB) + (size_t)sp * TPS * 256;

    #define LOADT(BUF, T)                                            \
        {                                                            \
            _Pragma("unroll")                                        \
            for (int ks = 0; ks < 4; ks++)                           \
                BUF[ks] = bbase[(size_t)(T) * 256 + ks * 64 + l];    \
        }

    #define COMP(BUF, T)                                                          \
        {                                                                         \
            f32x4 acc[4];                                                         \
            _Pragma("unroll")                                                     \
            for (int f = 0; f < 4; f++) acc[f] = (f32x4){0.f, 0.f, 0.f, 0.f};     \
            _Pragma("unroll")                                                     \
            for (int ks = 0; ks < 4; ks++)                                        \
                _Pragma("unroll")                                                 \
                for (int f = 0; f < 4; f++)                                       \
                    acc[f] = __builtin_amdgcn_mfma_f32_16x16x32_f16(a[f][ks], BUF[ks], acc[f], 0, 0, 0); \
            const unsigned tl = (unsigned)(T);                                    \
            _Pragma("unroll")                                                     \
            for (int f = 0; f < 4; f++)                                           \
                _Pragma("unroll")                                                 \
                for (int r = 0; r < 4; r++) {                                     \
                    int s = f * 4 + r;                                            \
                    float xq = __uint_as_float((__float_as_uint(acc[f][r]) & 0xFFFFFFE0u) | tl); \
                    v2[s] = __builtin_amdgcn_fmed3f(xq, v1[s], v2[s]);            \
                    v1[s] = fmaxf(v1[s], xq);                                     \
                }                                                                 \
        }

    f16x8 b0[4], b1[4], b2[4], b3[4];
    LOADT(b0, 0);
    LOADT(b1, 1);
    for (int t = 0; t < TPS; t += 4) {
        LOADT(b2, t + 2);
        LOADT(b3, t + 3);
        COMP(b0, t);
        COMP(b1, t + 1);
        if (t + 4 < TPS) { LOADT(b0, t + 4); LOADT(b1, t + 5); }
        COMP(b2, t + 2);
        COMP(b3, t + 3);
    }
    #undef LOADT
    #undef COMP

    float vv1[16], vv2[16];
    int jj1[16], jj2[16];
    const int col = l & 15;
    #pragma unroll
    for (int s = 0; s < 16; s++) {
        unsigned u1 = __float_as_uint(v1[s]);
        unsigned u2 = __float_as_uint(v2[s]);
        vv1[s] = __uint_as_float(u1 & 0xFFFFFFE0u);
        vv2[s] = __uint_as_float(u2 & 0xFFFFFFE0u);
        jj1[s] = (sp * TPS + (int)(u1 & 31u)) * 16 + col;
        jj2[s] = (sp * TPS + (int)(u2 & 31u)) * 16 + col;
    }

    #pragma unroll
    for (int m = 1; m <= 8; m <<= 1) {
        #pragma unroll
        for (int s = 0; s < 16; s++) {
            float ov1 = __shfl_xor(vv1[s], m);
            float ov2 = __shfl_xor(vv2[s], m);
            int   oi1 = __shfl_xor(jj1[s], m);
            int   oi2 = __shfl_xor(jj2[s], m);
            bool sel = ov1 > vv1[s];
            float lv  = sel ? vv1[s] : ov1;
            int   li  = sel ? jj1[s] : oi1;
            float wv2 = sel ? ov2 : vv2[s];
            int   wi2 = sel ? oi2 : jj2[s];
            vv1[s] = sel ? ov1 : vv1[s];
            jj1[s] = sel ? oi1 : jj1[s];
            bool s2 = lv > wv2;
            vv2[s] = s2 ? lv : wv2;
            jj2[s] = s2 ? li : wi2;
        }
    }

    if ((l & 15) == 0) {
        int q = l >> 4;
        #pragma unroll
        for (int f = 0; f < 4; f++)
            #pragma unroll
            for (int r = 0; r < 4; r++) {
                int s = f * 4 + r;
                int row = (rt0 + f) * 16 + q * 4 + r;
                float4 o;
                o.x = vv1[s];
                o.y = vv2[s];
                o.z = __int_as_float(jj1[s]);
                o.w = __int_as_float(jj2[s]);
                pq[(size_t)row * NSPLIT + sp] = o;
            }
    }
}

// ---------------------------------------------------------------- k_epilogue
// Merge 8-split top-2; flagged rows: fp64 rescore of all 16 candidates,
// PARALLEL across waves x candidates; att via f16 G gather;
// out = normalize(att @ assoc).
__global__ __launch_bounds__(256) void k_epilogue(const float4* __restrict__ pq,
                                                  const float* __restrict__ emb,
                                                  const float* __restrict__ atoms,
                                                  const double* __restrict__ invn64,
                                                  const float* __restrict__ invnF,
                                                  const f16* __restrict__ Gh,
                                                  const float* __restrict__ b_att,
                                                  float* __restrict__ out) {
    __shared__ __align__(16) float assoc[LL * DD];
    __shared__ __align__(16) float4 pqS[LL][NSPLIT];
    __shared__ double candV[LL][16];
    __shared__ int    candI[LL][16];
    __shared__ int   amaxS[LL];
    __shared__ float invS[LL];
    __shared__ float attS[LL];
    __shared__ float wsum[4][40];
    __shared__ float sqw[4];
    __shared__ int   flagCnt;
    __shared__ int   flagRow[LL];

    const int b = blockIdx.x, tid = threadIdx.x;
    const int wid = tid >> 6, lane = tid & 63;

    if (tid == 0) flagCnt = 0;
    for (int i = tid; i < LL * NSPLIT; i += 256)
        pqS[i >> 3][i & 7] = pq[(size_t)(b * LL + (i >> 3)) * NSPLIT + (i & 7)];
    __syncthreads();

    if (tid < LL) {
        float V1 = -3e38f, V2 = -3e38f;
        int I1 = 0;
        #pragma unroll
        for (int sp = 0; sp < NSPLIT; sp++) {
            float4 qv = pqS[tid][sp];
            float a1 = qv.x, a2 = qv.y;
            int   j1 = __float_as_int(qv.z);
            bool sel = a1 > V1;
            float lv  = sel ? V1 : a1;
            float wv2 = sel ? a2 : V2;
            V1 = sel ? a1 : V1;
            I1 = sel ? j1 : I1;
            V2 = fmaxf(lv, wv2);
        }
        amaxS[tid] = I1;
        if (V1 - V2 < TAU) {
            int k = atomicAdd(&flagCnt, 1);
            flagRow[k] = tid;
        }
    }
    __syncthreads();

    const int cnt = flagCnt;
    // parallel fp64 rescore: task j = (flag fi, candidate c); one wave per task
    for (int j = wid; j < cnt * 16; j += 4) {
        int fi = j >> 4, c = j & 15;
        int row = flagRow[fi];
        float4 qv = pqS[row][c >> 1];
        int idx = __float_as_int((c & 1) ? qv.w : qv.z);
        const float2 ev = ((const float2*)(emb + (size_t)(b * LL + row) * DD))[lane];
        const float2 av = ((const float2*)(atoms + (size_t)idx * DD))[lane];
        double p = (double)ev.x * av.x + (double)ev.y * av.y;
        #pragma unroll
        for (int m = 1; m <= 32; m <<= 1) p += __shfl_xor(p, m);
        if (lane == 0) {
            candV[fi][c] = p * invn64[idx];
            candI[fi][c] = idx;
        }
    }
    __syncthreads();
    if (tid < cnt) {
        double bv = -1e300;
        int bi = 0x7fffffff;
        #pragma unroll
        for (int c = 0; c < 16; c++) {
            double v = candV[tid][c];
            int    i = candI[tid][c];
            if (v > bv || (v == bv && i < bi)) { bv = v; bi = i; }
        }
        amaxS[flagRow[tid]] = bi;
    }
    __syncthreads();

    if (tid < LL) invS[tid] = invnF[amaxS[tid]];
    if (lane < LL) {
        float ga = 0.f;
        for (int ll = wid; ll < LL; ll += 4)
            ga += (float)Gh[((size_t)ll * 4096 + amaxS[ll]) * 36 + lane];
        wsum[wid][lane] = ga;
    }
    __syncthreads();

    for (int idx = tid; idx < LL * DD; idx += 256) {
        int ll = idx >> 7, d = idx & 127;
        assoc[idx] = atoms[(size_t)amaxS[ll] * DD + d] * invS[ll];
    }
    if (tid < LL)
        attS[tid] = b_att[tid] + wsum[0][tid] + wsum[1][tid] + wsum[2][tid] + wsum[3][tid];
    __syncthreads();

    float o = 0.0f;
    if (tid < DD) {
        #pragma unroll
        for (int ll = 0; ll < LL; ll++) o = fmaf(attS[ll], assoc[ll * DD + tid], o);
    }
    float sq = (tid < DD) ? o * o : 0.0f;
    #pragma unroll
    for (int off = 32; off; off >>= 1) sq += __shfl_xor(sq, off);
    if (lane == 0) sqw[wid] = sq;
    __syncthreads();
    float tot = sqw[0] + sqw[1] + sqw[2] + sqw[3];
    float n = sqrtf(tot);
    float inv = 1.0f / fmaxf(n, 1e-12f);
    if (tid < DD) out[(size_t)b * DD + tid] = o * inv;
}

// ---------------------------------------------------------------- launcher
extern "C" void kernel_launch(void* const* d_in, const int* in_sizes, int n_in,
                              void* d_out, int out_size, void* d_ws, size_t ws_size,
                              hipStream_t stream) {
    const float* emb   = (const float*)d_in[0];
    const float* atoms = (const float*)d_in[1];
    const float* W     = (const float*)d_in[2];
    const float* b_att = (const float*)d_in[3];
    float* out = (float*)d_out;

    char* ws = (char*)d_ws;
    f16x8*  embA   = (f16x8*)(ws + OFF_EMBA);
    char*   atomB  = (char*)(ws + OFF_ATOMB);
    f16x8*  wfrag  = (f16x8*)(ws + OFF_WFRAG);
    f16*    Gh     = (f16*)(ws + OFF_G);
    float4* pq     = (float4*)(ws + OFF_PQ);
    double* invn64 = (double*)(ws + OFF_INVN64);
    float*  invnF  = (float*)(ws + OFF_INVNF);

    k_prep<<<PREPEA + LL, 256, 0, stream>>>(emb, atoms, W, invn64, invnF,
                                            embA, (f16x8*)atomB, wfrag);
    k_score<<<SCOREBLKS + GTABBLKS, 256, 0, stream>>>(embA, atomB, wfrag, Gh, pq);
    k_epilogue<<<BB, 256, 0, stream>>>(pq, emb, atoms, invn64, invnF, Gh, b_att, out);
}

// Round 13
// 151.426 us; speedup vs baseline: 2.0338x; 2.0338x over previous
//
#include <hip/hip_runtime.h>
#include <math.h>

#define BB 1024
#define LL 34
#define DD 128
#define AA 4096
#define NROWS (BB * LL)        // 34816
#define RTILES (NROWS / 16)    // 2176 row tiles
#define ATILES (AA / 16)       // 256 atom tiles
#define NSPLIT 8
#define TPS (ATILES / NSPLIT)  // 32 tiles per split
#define TAU 2.5e-3f
#define SBLK ((RTILES / 8) * NSPLIT)         // 2176 score blocks (R=2/wave, 8 rt/block)
#define GTABBLKS (LL * 32)                   // 1088
#define PREPEA ((RTILES + ATILES) / 4)       // 608 blocks x 4 tiles

typedef _Float16 f16;
typedef _Float16 f16x8 __attribute__((ext_vector_type(8)));
typedef float f32x4  __attribute__((ext_vector_type(4)));

// ---- ws layout (bytes), total ~24.9 MB ----
#define OFF_EMBA   0u            // RTILES*4096 (f16 emb frags, A-layout)
#define OFF_ATOMB  8912896u      // ATILES*4096 (f16 atoms_n frags)
#define OFF_WFRAG  9961472u      // 34*3*4*64*16 (f16 W frags, B-layout, N pad 48)
#define OFF_G      10379264u     // 34*4096*36*2 = 10,027,008  (G[l][a][36] f16)
#define OFF_PQ     20406272u     // NROWS*NSPLIT*16
#define OFF_INVN64 24862720u
#define OFF_INVNF  24895488u

// ---------------------------------------------------------------- k_prep
// 4 tiles per block (608 blocks) + 34 W blocks. LDS-bounced coalesced loads.
__global__ __launch_bounds__(256) void k_prep(const float* __restrict__ emb,
                                              const float* __restrict__ atoms,
                                              const float* __restrict__ W,
                                              double* __restrict__ invn64,
                                              float* __restrict__ invnF,
                                              f16x8* __restrict__ embA,
                                              f16x8* __restrict__ atomB,
                                              f16x8* __restrict__ wfrag) {
    __shared__ __align__(16) float stbuf[4608];     // 18432 B
    __shared__ double part[16][17];
    const int bid = blockIdx.x;
    const int tid = threadIdx.x;

    if (bid < PREPEA) {                             // emb/atom tiles, 4 per block
        #pragma unroll 1
        for (int tt = 0; tt < 4; tt++) {
            const int gtile = bid * 4 + tt;         // 0..2431
            const bool isAtom = (gtile >= RTILES);
            const int tile = isAtom ? gtile - RTILES : gtile;
            const float* src = (isAtom ? atoms : emb) + (size_t)tile * 2048;
            float4* st4 = (float4*)stbuf;
            for (int i = tid; i < 512; i += 256) {  // coalesced 8 KB stage
                int row = i >> 5, c4 = i & 31;
                st4[row * 33 + c4] = ((const float4*)src)[i];
            }
            __syncthreads();

            const int ks = tid >> 6, l = tid & 63;
            const int m = l & 15, koff4 = ((l >> 4) << 1) + (ks << 3);
            float4 f0 = st4[m * 33 + koff4];
            float4 f1 = st4[m * 33 + koff4 + 1];
            float xs[8] = {f0.x, f0.y, f0.z, f0.w, f1.x, f1.y, f1.z, f1.w};

            if (!isAtom) {
                f16x8 h;
                #pragma unroll
                for (int j = 0; j < 8; j++) h[j] = (f16)xs[j];
                embA[(size_t)(tile * 4 + ks) * 64 + l] = h;
            } else {
                double ssq = 0.0;
                #pragma unroll
                for (int j = 0; j < 8; j++) ssq += (double)xs[j] * xs[j];
                part[m][ks * 4 + (l >> 4)] = ssq;
                __syncthreads();
                double tot = 0.0;
                #pragma unroll
                for (int q = 0; q < 16; q++) tot += part[m][q];
                double n = sqrt(tot);
                if (n < 1e-12) n = 1e-12;
                double inv = 1.0 / n;
                float invf = (float)inv;
                f16x8 h;
                #pragma unroll
                for (int j = 0; j < 8; j++) h[j] = (f16)(xs[j] * invf);
                if (ks == 0 && (l >> 4) == 0) {
                    invn64[tile * 16 + m] = inv;
                    invnF[tile * 16 + m] = invf;
                }
                atomB[(size_t)(tile * 4 + ks) * 64 + l] = h;
            }
            __syncthreads();                        // st4/part reuse guard
        }
    } else {                                        // W fragment build, one l
        const int l = bid - PREPEA;                 // 0..33
        const float* wsrc = W + (size_t)l * 128 * LL;
        for (int i = tid; i < 128 * LL; i += 256) { // coalesced 17.4 KB stage
            int row = i / LL, j = i - row * LL;
            stbuf[row * 35 + j] = wsrc[i];
        }
        __syncthreads();
        for (int s = tid; s < 768; s += 256) {
            int lane = s & 63, ksnt = s >> 6;
            int ks = ksnt & 3, nt = ksnt >> 2;
            int j = nt * 16 + (lane & 15);
            int kb = ks * 32 + ((lane >> 4) << 3);
            f16x8 h;
            if (j < LL) {
                #pragma unroll
                for (int jj = 0; jj < 8; jj++) h[jj] = (f16)stbuf[(kb + jj) * 35 + j];
            } else {
                #pragma unroll
                for (int jj = 0; jj < 8; jj++) h[jj] = (f16)0.f;
            }
            wfrag[(size_t)((l * 3 + nt) * 4 + ks) * 64 + lane] = h;
        }
    }
}

// ---------------------------------------------------------------- k_score
// Blocks [0,2176): barrier-free f16 MFMA screen, R=2 row-tiles/wave for high
// TLP (small VGPR footprint, launch_bounds(256,4)), depth-1 2-buffer register
// prefetch (the proven no-spill config). XCD swizzle bid = sp*272+rb
// (272%8==0) keeps each XCD's embA slice + atomB L2-resident.
// Blocks [2176,3264): G-table build (G[l][a][36] f16, LDS-staged linear).
__global__ __launch_bounds__(256, 4) void k_score(const f16x8* __restrict__ embA,
                                                  const char* __restrict__ atomB,
                                                  const f16x8* __restrict__ wfrag,
                                                  f16* __restrict__ Gh,
                                                  float4* __restrict__ pq) {
    const int tid = threadIdx.x;
    const int w = tid >> 6, l = tid & 63;

    if (blockIdx.x >= SBLK) {
        // ---------------- gtab path: 128 atoms x one l per block
        __shared__ __align__(16) float gs[128 * 36];   // 18432 B
        const int gb = blockIdx.x - SBLK;
        const int ll = gb >> 5, ab = gb & 31;

        f16x8 bw[3][4];
        #pragma unroll
        for (int nt = 0; nt < 3; nt++)
            #pragma unroll
            for (int ks = 0; ks < 4; ks++)
                bw[nt][ks] = wfrag[(size_t)((ll * 3 + nt) * 4 + ks) * 64 + l];

        const int col = l & 15, rq = (l >> 4) * 4;
        #pragma unroll
        for (int t = 0; t < 2; t++) {
            int atile = ab * 8 + w * 2 + t;
            f16x8 ah[4];
            #pragma unroll
            for (int ks = 0; ks < 4; ks++)
                ah[ks] = *(const f16x8*)(atomB + ((size_t)(atile * 4 + ks) * 64 + l) * 16);
            f32x4 acc[3];
            #pragma unroll
            for (int nt = 0; nt < 3; nt++) acc[nt] = (f32x4){0.f, 0.f, 0.f, 0.f};
            #pragma unroll
            for (int ks = 0; ks < 4; ks++)
                #pragma unroll
                for (int nt = 0; nt < 3; nt++)
                    acc[nt] = __builtin_amdgcn_mfma_f32_16x16x32_f16(ah[ks], bw[nt][ks], acc[nt], 0, 0, 0);
            int aloc0 = (w * 2 + t) * 16 + rq;
            #pragma unroll
            for (int nt = 0; nt < 3; nt++) {
                int j = nt * 16 + col;
                if (j < LL) {
                    #pragma unroll
                    for (int r = 0; r < 4; r++)
                        gs[(aloc0 + r) * 36 + j] = acc[nt][r];
                }
            }
        }
        __syncthreads();
        f16* Gl = Gh + ((size_t)ll * 4096 + ab * 128) * 36;
        for (int i = tid; i < 128 * 36; i += 256) Gl[i] = (f16)gs[i];
        return;
    }

    // ---------------- score path (no LDS, no __syncthreads), R=2
    const int sp = blockIdx.x / 272, rb = blockIdx.x - sp * 272;
    const int rt0 = rb * 8 + w * 2;

    f16x8 a[2][4];
    #pragma unroll
    for (int f = 0; f < 2; f++)
        #pragma unroll
        for (int ks = 0; ks < 4; ks++)
            a[f][ks] = embA[(size_t)((rt0 + f) * 4 + ks) * 64 + l];

    float v1[8], v2[8];
    #pragma unroll
    for (int s = 0; s < 8; s++) { v1[s] = -3e38f; v2[s] = -3e38f; }

    const f16x8* bbase = (const f16x8*)(atomB) + (size_t)sp * TPS * 256;

    #define LOADT(BUF, T)                                            \
        {                                                            \
            _Pragma("unroll")                                        \
            for (int ks = 0; ks < 4; ks++)                           \
                BUF[ks] = bbase[(size_t)(T) * 256 + ks * 64 + l];    \
        }

    #define COMP(BUF, T)                                                          \
        {                                                                         \
            f32x4 acc[2];                                                         \
            acc[0] = (f32x4){0.f, 0.f, 0.f, 0.f};                                 \
            acc[1] = (f32x4){0.f, 0.f, 0.f, 0.f};                                 \
            _Pragma("unroll")                                                     \
            for (int ks = 0; ks < 4; ks++)                                        \
                _Pragma("unroll")                                                 \
                for (int f = 0; f < 2; f++)                                       \
                    acc[f] = __builtin_amdgcn_mfma_f32_16x16x32_f16(a[f][ks], BUF[ks], acc[f], 0, 0, 0); \
            const unsigned tl = (unsigned)(T);                                    \
            _Pragma("unroll")                                                     \
            for (int f = 0; f < 2; f++)                                           \
                _Pragma("unroll")                                                 \
                for (int r = 0; r < 4; r++) {                                     \
                    int s = f * 4 + r;                                            \
                    float xq = __uint_as_float((__float_as_uint(acc[f][r]) & 0xFFFFFFE0u) | tl); \
                    v2[s] = __builtin_amdgcn_fmed3f(xq, v1[s], v2[s]);            \
                    v1[s] = fmaxf(v1[s], xq);                                     \
                }                                                                 \
        }

    f16x8 b0[4], b1[4];
    LOADT(b0, 0);
    for (int t = 0; t < TPS; t += 2) {
        LOADT(b1, t + 1);
        COMP(b0, t);
        if (t + 2 < TPS) LOADT(b0, t + 2);
        COMP(b1, t + 1);
    }
    #undef LOADT
    #undef COMP

    float vv1[8], vv2[8];
    int jj1[8], jj2[8];
    const int col = l & 15;
    #pragma unroll
    for (int s = 0; s < 8; s++) {
        unsigned u1 = __float_as_uint(v1[s]);
        unsigned u2 = __float_as_uint(v2[s]);
        vv1[s] = __uint_as_float(u1 & 0xFFFFFFE0u);
        vv2[s] = __uint_as_float(u2 & 0xFFFFFFE0u);
        jj1[s] = (sp * TPS + (int)(u1 & 31u)) * 16 + col;
        jj2[s] = (sp * TPS + (int)(u2 & 31u)) * 16 + col;
    }

    #pragma unroll
    for (int m = 1; m <= 8; m <<= 1) {
        #pragma unroll
        for (int s = 0; s < 8; s++) {
            float ov1 = __shfl_xor(vv1[s], m);
            float ov2 = __shfl_xor(vv2[s], m);
            int   oi1 = __shfl_xor(jj1[s], m);
            int   oi2 = __shfl_xor(jj2[s], m);
            bool sel = ov1 > vv1[s];
            float lv  = sel ? vv1[s] : ov1;
            int   li  = sel ? jj1[s] : oi1;
            float wv2 = sel ? ov2 : vv2[s];
            int   wi2 = sel ? oi2 : jj2[s];
            vv1[s] = sel ? ov1 : vv1[s];
            jj1[s] = sel ? oi1 : jj1[s];
            bool s2 = lv > wv2;
            vv2[s] = s2 ? lv : wv2;
            jj2[s] = s2 ? li : wi2;
        }
    }

    if ((l & 15) == 0) {
        int q = l >> 4;
        #pragma unroll
        for (int f = 0; f < 2; f++)
            #pragma unroll
            for (int r = 0; r < 4; r++) {
                int s = f * 4 + r;
                int row = (rt0 + f) * 16 + q * 4 + r;
                float4 o;
                o.x = vv1[s];
                o.y = vv2[s];
                o.z = __int_as_float(jj1[s]);
                o.w = __int_as_float(jj2[s]);
                pq[(size_t)row * NSPLIT + sp] = o;
            }
    }
}

// ---------------------------------------------------------------- k_epilogue
// Merge 8-split top-2; flagged rows: fp64 rescore of all 16 candidates,
// parallel across waves x candidates; att via f16 G gather;
// out = normalize(att @ assoc).
__global__ __launch_bounds__(256) void k_epilogue(const float4* __restrict__ pq,
                                                  const float* __restrict__ emb,
                                                  const float* __restrict__ atoms,
                                                  const double* __restrict__ invn64,
                                                  const float* __restrict__ invnF,
                                                  const f16* __restrict__ Gh,
                                                  const float* __restrict__ b_att,
                                                  float* __restrict__ out) {
    __shared__ __align__(16) float assoc[LL * DD];
    __shared__ __align__(16) float4 pqS[LL][NSPLIT];
    __shared__ double candV[LL][16];
    __shared__ int    candI[LL][16];
    __shared__ int   amaxS[LL];
    __shared__ float invS[LL];
    __shared__ float attS[LL];
    __shared__ float wsum[4][40];
    __shared__ float sqw[4];
    __shared__ int   flagCnt;
    __shared__ int   flagRow[LL];

    const int b = blockIdx.x, tid = threadIdx.x;
    const int wid = tid >> 6, lane = tid & 63;

    if (tid == 0) flagCnt = 0;
    for (int i = tid; i < LL * NSPLIT; i += 256)
        pqS[i >> 3][i & 7] = pq[(size_t)(b * LL + (i >> 3)) * NSPLIT + (i & 7)];
    __syncthreads();

    if (tid < LL) {
        float V1 = -3e38f, V2 = -3e38f;
        int I1 = 0;
        #pragma unroll
        for (int sp = 0; sp < NSPLIT; sp++) {
            float4 qv = pqS[tid][sp];
            float a1 = qv.x, a2 = qv.y;
            int   j1 = __float_as_int(qv.z);
            bool sel = a1 > V1;
            float lv  = sel ? V1 : a1;
            float wv2 = sel ? a2 : V2;
            V1 = sel ? a1 : V1;
            I1 = sel ? j1 : I1;
            V2 = fmaxf(lv, wv2);
        }
        amaxS[tid] = I1;
        if (V1 - V2 < TAU) {
            int k = atomicAdd(&flagCnt, 1);
            flagRow[k] = tid;
        }
    }
    __syncthreads();

    const int cnt = flagCnt;
    for (int j = wid; j < cnt * 16; j += 4) {
        int fi = j >> 4, c = j & 15;
        int row = flagRow[fi];
        float4 qv = pqS[row][c >> 1];
        int idx = __float_as_int((c & 1) ? qv.w : qv.z);
        const float2 ev = ((const float2*)(emb + (size_t)(b * LL + row) * DD))[lane];
        const float2 av = ((const float2*)(atoms + (size_t)idx * DD))[lane];
        double p = (double)ev.x * av.x + (double)ev.y * av.y;
        #pragma unroll
        for (int m = 1; m <= 32; m <<= 1) p += __shfl_xor(p, m);
        if (lane == 0) {
            candV[fi][c] = p * invn64[idx];
            candI[fi][c] = idx;
        }
    }
    __syncthreads();
    if (tid < cnt) {
        double bv = -1e300;
        int bi = 0x7fffffff;
        #pragma unroll
        for (int c = 0; c < 16; c++) {
            double v = candV[tid][c];
            int    i = candI[tid][c];
            if (v > bv || (v == bv && i < bi)) { bv = v; bi = i; }
        }
        amaxS[flagRow[tid]] = bi;
    }
    __syncthreads();

    if (tid < LL) invS[tid] = invnF[amaxS[tid]];
    if (lane < LL) {
        float ga = 0.f;
        for (int ll = wid; ll < LL; ll += 4)
            ga += (float)Gh[((size_t)ll * 4096 + amaxS[ll]) * 36 + lane];
        wsum[wid][lane] = ga;
    }
    __syncthreads();

    for (int idx = tid; idx < LL * DD; idx += 256) {
        int ll = idx >> 7, d = idx & 127;
        assoc[idx] = atoms[(size_t)amaxS[ll] * DD + d] * invS[ll];
    }
    if (tid < LL)
        attS[tid] = b_att[tid] + wsum[0][tid] + wsum[1][tid] + wsum[2][tid] + wsum[3][tid];
    __syncthreads();

    float o = 0.0f;
    if (tid < DD) {
        #pragma unroll
        for (int ll = 0; ll < LL; ll++) o = fmaf(attS[ll], assoc[ll * DD + tid], o);
    }
    float sq = (tid < DD) ? o * o : 0.0f;
    #pragma unroll
    for (int off = 32; off; off >>= 1) sq += __shfl_xor(sq, off);
    if (lane == 0) sqw[wid] = sq;
    __syncthreads();
    float tot = sqw[0] + sqw[1] + sqw[2] + sqw[3];
    float n = sqrtf(tot);
    float inv = 1.0f / fmaxf(n, 1e-12f);
    if (tid < DD) out[(size_t)b * DD + tid] = o * inv;
}

// ---------------------------------------------------------------- launcher
extern "C" void kernel_launch(void* const* d_in, const int* in_sizes, int n_in,
                              void* d_out, int out_size, void* d_ws, size_t ws_size,
                              hipStream_t stream) {
    const float* emb   = (const float*)d_in[0];
    const float* atoms = (const float*)d_in[1];
    const float* W     = (const float*)d_in[2];
    const float* b_att = (const float*)d_in[3];
    float* out = (float*)d_out;

    char* ws = (char*)d_ws;
    f16x8*  embA   = (f16x8*)(ws + OFF_EMBA);
    char*   atomB  = (char*)(ws + OFF_ATOMB);
    f16x8*  wfrag  = (f16x8*)(ws + OFF_WFRAG);
    f16*    Gh     = (f16*)(ws + OFF_G);
    float4* pq     = (float4*)(ws + OFF_PQ);
    double* invn64 = (double*)(ws + OFF_INVN64);
    float*  invnF  = (float*)(ws + OFF_INVNF);

    k_prep<<<PREPEA + LL, 256, 0, stream>>>(emb, atoms, W, invn64, invnF,
                                            embA, (f16x8*)atomB, wfrag);
    k_score<<<SBLK + GTABBLKS, 256, 0, stream>>>(embA, atomB, wfrag, Gh, pq);
    k_epilogue<<<BB, 256, 0, stream>>>(pq, emb, atoms, invn64, invnF, Gh, b_att, out);
}